// Round 8
// baseline (1164.498 us; speedup 1.0000x reference)
//
#include <hip/hip_runtime.h>
#include <hip/hip_bf16.h>

typedef __attribute__((ext_vector_type(8))) short short8;
typedef __attribute__((ext_vector_type(4))) float f32x4;
typedef __attribute__((ext_vector_type(4))) int  i32x4;

// B=32, C=64, N=4096, K=2049, modes=64
constexpr int NSEQ  = 4096;
constexpr int KHT   = 2049;
constexpr int TABST = 2080;
constexpr int BATCH = 32;
constexpr int NROWS = 2048;   // rows 0..2047 in MFMA GEMM; row 2048 via gemv
constexpr float TPI = 6.283185307179586f;   // fp32(2*pi), matches reference chain

constexpr size_t PLANE_USH = (size_t)512 * NROWS * 8;      // 8,388,608 shorts/plane

// ws layout in float units (~69.2 MB)
constexpr size_t COSP_OFF = 3 * PLANE_USH / 2;             // 12,582,912
constexpr size_t COSP_SZ  = (size_t)KHT * 2048;            // 4,196,352
constexpr size_t XH_OFF   = COSP_OFF + COSP_SZ;
constexpr size_t XH_SZ    = (size_t)64 * 2048;
constexpr size_t TAB_OFF  = XH_OFF + XH_SZ;
constexpr size_t TAB_SZ   = (size_t)128 * TABST;
constexpr size_t OH_OFF   = TAB_OFF + TAB_SZ;

// ---- 3-way bf16 split via bit-truncation: exact decomposition of fp32 ------
__device__ __forceinline__ void split3t(float v, short &h0, short &h1, short &h2) {
  unsigned u  = __builtin_bit_cast(unsigned, v);
  unsigned u0 = u & 0xFFFF0000u;
  float f0 = __builtin_bit_cast(float, u0);
  float r1 = v - f0;                       // exact
  unsigned u1 = __builtin_bit_cast(unsigned, r1) & 0xFFFF0000u;
  float f1 = __builtin_bit_cast(float, u1);
  float r2 = r1 - f1;                      // exact
  h0 = (short)(u0 >> 16);
  h1 = (short)(u1 >> 16);
  h2 = (short)(__builtin_bit_cast(unsigned, r2) >> 16);
}

__device__ __forceinline__ void gl_lds16(const short* g, short* s) {
  __builtin_amdgcn_global_load_lds((const __attribute__((address_space(1))) void*)g,
                                   (__attribute__((address_space(3))) void*)s, 16, 0, 0);
}

__device__ __forceinline__ int rot16(int x) {
  return (int)(((unsigned)x >> 16) | ((unsigned)x << 16));
}

// ---------------- prep: cas_N split planes, slab-major [k/8][row][8] --------
__global__ __launch_bounds__(256) void prep_A(short* __restrict__ Aq) {
  int row  = blockIdx.x * 256 + threadIdx.x;     // 0..2047
  int slab = blockIdx.y;
  short8 o0, o1, o2;
  float t1 = TPI * (float)row;             // fl32(2pi*n), n = row first!
  #pragma unroll
  for (int e = 0; e < 8; ++e) {
    float t2  = t1 * (float)(slab * 8 + e);     // fl32(t1*p)
    float arg = t2 * (1.0f / 4096.0f);          // exact pow2 divide
    float v = cosf(arg) + sinf(arg);
    short h0, h1, h2; split3t(v, h0, h1, h2);
    o0[e] = h0; o1[e] = h1; o2[e] = h2;
  }
  size_t base = (size_t)slab * (NROWS * 8) + (size_t)row * 8;
  *(short8*)(Aq + base)                  = o0;
  *(short8*)(Aq + PLANE_USH + base)      = o1;
  *(short8*)(Aq + 2 * PLANE_USH + base)  = o2;
}

// ---------------- prep: cas_K sparse-column table, 1/K folded in ------------
__global__ __launch_bounds__(256) void prep_tab(float* __restrict__ tab) {
  int idx = blockIdx.x * 256 + threadIdx.x;
  if (idx >= 128 * TABST) return;
  int j  = idx / TABST;
  int np = idx - j * TABST;
  float v = 0.0f;
  if (np < KHT) {
    int c = j >> 1, b = j & 1;
    int pp = 32 * c + b;
    float t1  = TPI * (float)np;
    float t2  = t1 * (float)pp;
    float arg = t2 / 2049.0f;
    v = (cosf(arg) + sinf(arg)) * (1.0f / 2049.0f);
  }
  tab[idx] = v;
}

// ---------------- MFMA GEMM + fused cos(atan2) epilogue ---------------------
// 512 thr, 8 waves: wr=w>>2 (row half), chh=(w>>1)&1 (channel half), var=w&1.
// Block: rows bm..bm+127, channels d2*128..+127 (2 batches), both variants.
// As double-buffered (issue-early via gl_lds); Bs single (split3t staged).
__global__ __launch_bounds__(512, 2) void gemm_mfma(const short* __restrict__ Aq,
                                                    const float* __restrict__ x,
                                                    float* __restrict__ cosp,
                                                    float* __restrict__ xh64) {
  __shared__ __align__(16) short lds[2 * 24576 + 24576];   // As dbuf 96KB + Bs 48KB
  short* Bs = lds + 49152;         // [p*8192 + s*1024 + mc*8 + e]
  const int t    = threadIdx.x;
  const int lane = t & 63;
  const int w    = t >> 6;
  const int wr   = w >> 2;                 // 0..1 row-half
  const int chh  = (w >> 1) & 1;           // channel half
  const int var  = w & 1;                  // 0=normal(a), 1=flip(b)
  const int bm   = blockIdx.y * 128;
  const int d2   = blockIdx.x;             // 128-channel chunk (2 batches)

  // B staging: thread stages channel mc, slabs {s0, s0+4}
  const int mc   = t & 127;
  const int s0   = t >> 7;                 // 0..3
  const float* xb = x + (d2 * 2 + (mc >> 6)) * 262144;
  const int mphys = mc & 63;

  f32x4 accM[4][4] = {};   // a0*b0 (large partials)
  f32x4 accL[4][4] = {};   // the 5 small products
  float breg[16];

  auto issueA = [&](int kt, int buf) {
    short* Ab = lds + buf * 24576;
    #pragma unroll
    for (int i = 0; i < 6; ++i) {
      int q = w * 6 + i;                   // 0..47 = p*16 + s*2 + h
      int p = q >> 4, s = (q >> 1) & 7, h = q & 1;
      const short* gp = Aq + (size_t)p * PLANE_USH + (size_t)(kt * 8 + s) * (NROWS * 8)
                        + (size_t)(bm + h * 64 + lane) * 8;
      gl_lds16(gp, &Ab[p * 8192 + s * 1024 + h * 512]);
    }
  };
  auto issueB = [&](int kt) {
    #pragma unroll
    for (int g = 0; g < 2; ++g) {
      int s = s0 + 4 * g;
      #pragma unroll
      for (int e = 0; e < 8; ++e)
        breg[g * 8 + e] = xb[((kt * 64 + s * 8 + e) << 6) + mphys];
    }
  };
  auto writeB = [&]() {
    #pragma unroll
    for (int g = 0; g < 2; ++g) {
      int s = s0 + 4 * g;
      short8 p0, p1, p2;
      #pragma unroll
      for (int e = 0; e < 8; ++e) {
        short h0, h1, h2; split3t(breg[g * 8 + e], h0, h1, h2);
        p0[e] = h0; p1[e] = h1; p2[e] = h2;
      }
      int bi = s * 1024 + mc * 8;
      *(short8*)&Bs[bi]         = p0;
      *(short8*)&Bs[8192 + bi]  = p1;
      *(short8*)&Bs[16384 + bi] = p2;
    }
  };
  auto compute = [&](int buf) {
    const short* Ab = lds + buf * 24576;
    #pragma unroll
    for (int u = 0; u < 2; ++u) {
      const int sg = 4 * u + (lane >> 4);
      short8 fa0[4], fa1[4], fa2[4];
      #pragma unroll
      for (int f = 0; f < 4; ++f) {
        int ai = sg * 1024 + (wr * 64 + f * 16 + (lane & 15)) * 8;
        fa0[f] = *(const short8*)&Ab[ai];
        fa1[f] = *(const short8*)&Ab[8192 + ai];
        fa2[f] = *(const short8*)&Ab[16384 + ai];
      }
      short8 fb[4];
      #pragma unroll
      for (int p = 0; p < 3; ++p) {
        #pragma unroll
        for (int f = 0; f < 4; ++f) {
          if (var == 0) {
            fb[f] = *(const short8*)&Bs[p * 8192 + sg * 1024
                                        + (chh * 64 + f * 16 + (lane & 15)) * 8];
          } else {
            short8 v = *(const short8*)&Bs[p * 8192 + (7 - sg) * 1024
                                           + (chh * 64 + 63 - (f * 16 + (lane & 15))) * 8];
            i32x4 vi = __builtin_bit_cast(i32x4, v);
            i32x4 wo;
            wo.x = rot16(vi.w); wo.y = rot16(vi.z);
            wo.z = rot16(vi.y); wo.w = rot16(vi.x);
            fb[f] = __builtin_bit_cast(short8, wo);
          }
        }
        if (p == 0) {
          #pragma unroll
          for (int fi = 0; fi < 4; ++fi)
            #pragma unroll
            for (int fj = 0; fj < 4; ++fj) {
              accM[fi][fj] = __builtin_amdgcn_mfma_f32_16x16x32_bf16(fa0[fi], fb[fj], accM[fi][fj], 0, 0, 0);
              accL[fi][fj] = __builtin_amdgcn_mfma_f32_16x16x32_bf16(fa1[fi], fb[fj], accL[fi][fj], 0, 0, 0);
              accL[fi][fj] = __builtin_amdgcn_mfma_f32_16x16x32_bf16(fa2[fi], fb[fj], accL[fi][fj], 0, 0, 0);
            }
        } else if (p == 1) {
          #pragma unroll
          for (int fi = 0; fi < 4; ++fi)
            #pragma unroll
            for (int fj = 0; fj < 4; ++fj) {
              accL[fi][fj] = __builtin_amdgcn_mfma_f32_16x16x32_bf16(fa0[fi], fb[fj], accL[fi][fj], 0, 0, 0);
              accL[fi][fj] = __builtin_amdgcn_mfma_f32_16x16x32_bf16(fa1[fi], fb[fj], accL[fi][fj], 0, 0, 0);
            }
        } else {
          #pragma unroll
          for (int fi = 0; fi < 4; ++fi)
            #pragma unroll
            for (int fj = 0; fj < 4; ++fj)
              accL[fi][fj] = __builtin_amdgcn_mfma_f32_16x16x32_bf16(fa0[fi], fb[fj], accL[fi][fj], 0, 0, 0);
        }
      }
    }
  };

  // prologue: stage tile 0
  issueB(0);
  issueA(0, 0);
  writeB();               // compiler waits the 16 B loads
  __syncthreads();        // drains gl_lds (As[0]) + ds_writes (Bs)

  for (int kt = 0; kt < 64; ++kt) {
    if (kt < 63) { issueB(kt + 1); issueA(kt + 1, (kt + 1) & 1); }
    __builtin_amdgcn_sched_barrier(0);     // pin issues ABOVE the MFMA cluster
    __builtin_amdgcn_s_setprio(1);
    compute(kt & 1);
    __builtin_amdgcn_s_setprio(0);
    __syncthreads();      // Bs reads done; vmcnt drain is free (~7k cyc old)
    if (kt < 63) writeB();
    __syncthreads();      // Bs(kt+1) + As[(kt+1)&1] visible
  }

  // ---- epilogue: var=1 publishes b via LDS; var=0 fuses cos(atan2) ----
  float* bx = (float*)lds;           // 64 KB exchange (As region dead)
  const int g = wr * 2 + chh;
  if (var) {
    #pragma unroll
    for (int fi = 0; fi < 4; ++fi)
      #pragma unroll
      for (int fj = 0; fj < 4; ++fj)
        #pragma unroll
        for (int r = 0; r < 4; ++r)
          bx[g * 4096 + (fi * 16 + ((lane >> 4) << 2) + r) * 64 + fj * 16 + (lane & 15)]
            = accM[fi][fj][r] + accL[fi][fj][r];
  }
  __syncthreads();
  if (!var) {
    #pragma unroll
    for (int fi = 0; fi < 4; ++fi) {
      #pragma unroll
      for (int fj = 0; fj < 4; ++fj) {
        #pragma unroll
        for (int r = 0; r < 4; ++r) {
          int rl = fi * 16 + ((lane >> 4) << 2) + r;
          int cl = fj * 16 + (lane & 15);
          float a = accM[fi][fj][r] + accL[fi][fj][r];
          float b = bx[g * 4096 + rl * 64 + cl];
          float r2 = a * a + b * b;
          float cp = (r2 > 0.0f) ? (a / sqrtf(r2)) : 1.0f;   // cos(atan2(b,a))
          int row = bm + wr * 64 + rl;
          int c   = d2 * 128 + chh * 64 + cl;
          cosp[(size_t)row * 2048 + c] = cp;
          if (bm == 0 && wr == 0) xh64[row * 2048 + c] = a;
        }
      }
    }
  }
}

// ---------------- row n=2048: fp32 GEMV for a,b -> cosp[2048][.] ------------
__global__ __launch_bounds__(256) void gemv2048(const float* __restrict__ x,
                                                float* __restrict__ cosp) {
  __shared__ float casL[4096];
  __shared__ float sv[256];
  const int t = threadIdx.x;
  const int d = blockIdx.x;                // batch
  const float t1 = TPI * 2048.0f;          // exact (pow2 scale)
  #pragma unroll
  for (int e = 0; e < 16; ++e) {
    int p = t + 256 * e;
    float arg = (t1 * (float)p) * (1.0f / 4096.0f);
    casL[p] = cosf(arg) + sinf(arg);
  }
  __syncthreads();
  const int m   = t & 63;
  const int vr  = (t >> 6) & 1;
  const int kh  = t >> 7;
  const float* xb = x + d * 262144;
  float s = 0.0f;
  for (int p = kh * 2048; p < kh * 2048 + 2048; ++p) {
    int j2 = p * 64 + m;
    int off = vr ? ((j2 & ~4095) + 4095 - (j2 & 4095)) : j2;
    s += casL[p] * xb[off];
  }
  sv[t] = s;
  __syncthreads();
  if (t < 128) sv[t] += sv[t + 128];
  __syncthreads();
  if (t < 64) {
    float a = sv[t], b = sv[64 + t];
    float r2 = a * a + b * b;
    float cp = (r2 > 0.0f) ? (a / sqrtf(r2)) : 1.0f;
    cosp[(size_t)2048 * 2048 + d * 64 + t] = cp;
  }
}

// ---------------- compl_mul: out_ht[b,o,m], modes=64 ------------------------
__global__ __launch_bounds__(256) void complmul(const float* __restrict__ xh64,
                                                const float* __restrict__ W,
                                                float* __restrict__ oh) {
  __shared__ float cl[64 * 65];
  const int t  = threadIdx.x;
  const int bq = blockIdx.y;
  const int og = blockIdx.x;
  #pragma unroll
  for (int e = 0; e < 16; ++e) {
    int idx = t + e * 256;
    int i = idx & 63, m = idx >> 6;
    cl[m * 65 + i] = xh64[m * 2048 + bq * 64 + i];
  }
  __syncthreads();
  const int m  = t & 63;
  const int o  = og * 4 + (t >> 6);
  const int mn = (64 - m) & 63;
  float s = 0.0f;
  for (int i = 0; i < 64; ++i) {
    float w  = W[i * 4096 + o * 64 + m];
    float wn = W[i * 4096 + o * 64 + mn];
    s += cl[m * 65 + i] * (w + wn) + cl[mn * 65 + i] * (w - wn);
  }
  oh[bq * 4096 + o * 64 + m] = 0.5f * s;
}

// ---------------- final: xi (sparse 64-term) * cosp -------------------------
__global__ __launch_bounds__(256) void final_k(const float* __restrict__ cosp,
                                               const float* __restrict__ tab,
                                               const float* __restrict__ oh,
                                               float* __restrict__ out) {
  __shared__ float tl[128 * 32];
  __shared__ float ol[64 * 64];
  const int t  = threadIdx.x;
  const int d  = blockIdx.y;
  const int n0 = blockIdx.x * 32;
  #pragma unroll
  for (int e = 0; e < 16; ++e) {
    int idx = t + e * 256;
    tl[idx] = tab[(idx >> 5) * TABST + n0 + (idx & 31)];
  }
  #pragma unroll
  for (int e = 0; e < 16; ++e) {
    int idx = t + e * 256;
    ol[idx] = oh[d * 4096 + idx];
  }
  __syncthreads();
  const int mp   = t & 63;
  const int nsub = t >> 6;

  float ohreg[64];
  #pragma unroll
  for (int c = 0; c < 64; ++c)
    ohreg[c] = ol[c * 64 + ((mp - c) & 63)];

  float acc[8] = {};
  #pragma unroll
  for (int c = 0; c < 64; ++c) {
    const float* tp = &tl[(2 * c + (c > mp ? 1 : 0)) * 32 + nsub * 8];
    float tv[8];
    *(float4*)&tv[0] = *(const float4*)tp;
    *(float4*)&tv[4] = *(const float4*)(tp + 4);
    #pragma unroll
    for (int q = 0; q < 8; ++q) acc[q] += tv[q] * ohreg[c];
  }
  #pragma unroll
  for (int q = 0; q < 8; ++q) {
    int np = n0 + nsub * 8 + q;
    if (np < KHT) {
      float cp = cosp[(size_t)np * 2048 + d * 64 + mp];
      out[d * 131136 + mp * 2049 + np] = acc[q] * cp;
    }
  }
}

extern "C" void kernel_launch(void* const* d_in, const int* in_sizes, int n_in,
                              void* d_out, int out_size, void* d_ws, size_t ws_size,
                              hipStream_t stream) {
  const float* x = (const float*)d_in[0];     // (32, 64, 4096) f32
  const float* W = (const float*)d_in[1];     // (64, 64, 64) f32
  float* out = (float*)d_out;                 // (32, 64, 2049) f32
  float* ws  = (float*)d_ws;

  short* Aq    = (short*)ws;
  float* cospB = ws + COSP_OFF;
  float* xh64  = ws + XH_OFF;
  float* tab   = ws + TAB_OFF;
  float* oh    = ws + OH_OFF;

  prep_A   <<<dim3(8, 512), dim3(256), 0, stream>>>(Aq);
  prep_tab <<<dim3((128 * TABST + 255) / 256), dim3(256), 0, stream>>>(tab);
  gemm_mfma<<<dim3(16, 16), dim3(512), 0, stream>>>(Aq, x, cospB, xh64);
  gemv2048 <<<dim3(BATCH), dim3(256), 0, stream>>>(x, cospB);
  complmul <<<dim3(16, BATCH), dim3(256), 0, stream>>>(xh64, W, oh);
  final_k  <<<dim3(65, BATCH), dim3(256), 0, stream>>>(cospB, tab, oh, out);
}

// Round 11
// 752.536 us; speedup vs baseline: 1.5474x; 1.5474x over previous
//
#include <hip/hip_runtime.h>
#include <hip/hip_bf16.h>

typedef __attribute__((ext_vector_type(8))) short short8;
typedef __attribute__((ext_vector_type(4))) float f32x4;
typedef __attribute__((ext_vector_type(4))) int  i32x4;

// B=32, C=64, N=4096, K=2049, modes=64
constexpr int NSEQ  = 4096;
constexpr int KHT   = 2049;
constexpr int TABST = 2080;
constexpr int BATCH = 32;
constexpr int NROWS = 2048;   // rows 0..2047 in MFMA GEMM; row 2048 via gemv
constexpr float TPI = 6.283185307179586f;   // fp32(2*pi), matches reference chain

constexpr size_t PLANE_USH = (size_t)512 * NROWS * 8;      // 8,388,608 shorts/plane

// ws layout in float units (~69.5 MB)
constexpr size_t COSP_OFF = 3 * PLANE_USH / 2;             // 12,582,912
constexpr size_t COSP_SZ  = (size_t)KHT * 2048;            // 4,196,352
constexpr size_t XH_OFF   = COSP_OFF + COSP_SZ;
constexpr size_t XH_SZ    = (size_t)64 * 2048;
constexpr size_t TAB_OFF  = XH_OFF + XH_SZ;
constexpr size_t TAB_SZ   = (size_t)128 * TABST;
constexpr size_t OH_OFF   = TAB_OFF + TAB_SZ;
constexpr size_t OH_SZ    = (size_t)BATCH * 64 * 64;
constexpr size_t P_OFF    = OH_OFF + OH_SZ;                // gemv partials [16][32][128]

// ---- 3-way bf16 split via bit-truncation: exact decomposition of fp32 ------
__device__ __forceinline__ void split3t(float v, short &h0, short &h1, short &h2) {
  unsigned u  = __builtin_bit_cast(unsigned, v);
  unsigned u0 = u & 0xFFFF0000u;
  float f0 = __builtin_bit_cast(float, u0);
  float r1 = v - f0;                       // exact
  unsigned u1 = __builtin_bit_cast(unsigned, r1) & 0xFFFF0000u;
  float f1 = __builtin_bit_cast(float, u1);
  float r2 = r1 - f1;                      // exact
  h0 = (short)(u0 >> 16);
  h1 = (short)(u1 >> 16);
  h2 = (short)(__builtin_bit_cast(unsigned, r2) >> 16);
}

__device__ __forceinline__ void gl_lds16(const short* g, short* s) {
  __builtin_amdgcn_global_load_lds((const __attribute__((address_space(1))) void*)g,
                                   (__attribute__((address_space(3))) void*)s, 16, 0, 0);
}

__device__ __forceinline__ int rot16(int x) {
  return (int)(((unsigned)x >> 16) | ((unsigned)x << 16));
}

// ---------------- prep: cas_N split planes, slab-major [k/8][row][8] --------
__global__ __launch_bounds__(256) void prep_A(short* __restrict__ Aq) {
  int row  = blockIdx.x * 256 + threadIdx.x;     // 0..2047
  int slab = blockIdx.y;
  short8 o0, o1, o2;
  float t1 = TPI * (float)row;             // fl32(2pi*n), n = row first!
  #pragma unroll
  for (int e = 0; e < 8; ++e) {
    float t2  = t1 * (float)(slab * 8 + e);     // fl32(t1*p)
    float arg = t2 * (1.0f / 4096.0f);          // exact pow2 divide
    float v = cosf(arg) + sinf(arg);
    short h0, h1, h2; split3t(v, h0, h1, h2);
    o0[e] = h0; o1[e] = h1; o2[e] = h2;
  }
  size_t base = (size_t)slab * (NROWS * 8) + (size_t)row * 8;
  *(short8*)(Aq + base)                  = o0;
  *(short8*)(Aq + PLANE_USH + base)      = o1;
  *(short8*)(Aq + 2 * PLANE_USH + base)  = o2;
}

// ---------------- prep: cas_K sparse-column table, 1/K folded in ------------
__global__ __launch_bounds__(256) void prep_tab(float* __restrict__ tab) {
  int idx = blockIdx.x * 256 + threadIdx.x;
  if (idx >= 128 * TABST) return;
  int j  = idx / TABST;
  int np = idx - j * TABST;
  float v = 0.0f;
  if (np < KHT) {
    int c = j >> 1, b = j & 1;
    int pp = 32 * c + b;
    float t1  = TPI * (float)np;
    float t2  = t1 * (float)pp;
    float arg = t2 / 2049.0f;
    v = (cosf(arg) + sinf(arg)) * (1.0f / 2049.0f);
  }
  tab[idx] = v;
}

// ---------------- MFMA GEMM + fused cos(atan2) epilogue ---------------------
// (byte-identical to round 8 -- measured 483 us, MfmaUtil 37)
__global__ __launch_bounds__(512, 2) void gemm_mfma(const short* __restrict__ Aq,
                                                    const float* __restrict__ x,
                                                    float* __restrict__ cosp,
                                                    float* __restrict__ xh64) {
  __shared__ __align__(16) short lds[2 * 24576 + 24576];   // As dbuf 96KB + Bs 48KB
  short* Bs = lds + 49152;         // [p*8192 + s*1024 + mc*8 + e]
  const int t    = threadIdx.x;
  const int lane = t & 63;
  const int w    = t >> 6;
  const int wr   = w >> 2;                 // 0..1 row-half
  const int chh  = (w >> 1) & 1;           // channel half
  const int var  = w & 1;                  // 0=normal(a), 1=flip(b)
  const int bm   = blockIdx.y * 128;
  const int d2   = blockIdx.x;             // 128-channel chunk (2 batches)

  const int mc   = t & 127;
  const int s0   = t >> 7;                 // 0..3
  const float* xb = x + (d2 * 2 + (mc >> 6)) * 262144;
  const int mphys = mc & 63;

  f32x4 accM[4][4] = {};   // a0*b0 (large partials)
  f32x4 accL[4][4] = {};   // the 5 small products
  float breg[16];

  auto issueA = [&](int kt, int buf) {
    short* Ab = lds + buf * 24576;
    #pragma unroll
    for (int i = 0; i < 6; ++i) {
      int q = w * 6 + i;                   // 0..47 = p*16 + s*2 + h
      int p = q >> 4, s = (q >> 1) & 7, h = q & 1;
      const short* gp = Aq + (size_t)p * PLANE_USH + (size_t)(kt * 8 + s) * (NROWS * 8)
                        + (size_t)(bm + h * 64 + lane) * 8;
      gl_lds16(gp, &Ab[p * 8192 + s * 1024 + h * 512]);
    }
  };
  auto issueB = [&](int kt) {
    #pragma unroll
    for (int g = 0; g < 2; ++g) {
      int s = s0 + 4 * g;
      #pragma unroll
      for (int e = 0; e < 8; ++e)
        breg[g * 8 + e] = xb[((kt * 64 + s * 8 + e) << 6) + mphys];
    }
  };
  auto writeB = [&]() {
    #pragma unroll
    for (int g = 0; g < 2; ++g) {
      int s = s0 + 4 * g;
      short8 p0, p1, p2;
      #pragma unroll
      for (int e = 0; e < 8; ++e) {
        short h0, h1, h2; split3t(breg[g * 8 + e], h0, h1, h2);
        p0[e] = h0; p1[e] = h1; p2[e] = h2;
      }
      int bi = s * 1024 + mc * 8;
      *(short8*)&Bs[bi]         = p0;
      *(short8*)&Bs[8192 + bi]  = p1;
      *(short8*)&Bs[16384 + bi] = p2;
    }
  };
  auto compute = [&](int buf) {
    const short* Ab = lds + buf * 24576;
    #pragma unroll
    for (int u = 0; u < 2; ++u) {
      const int sg = 4 * u + (lane >> 4);
      short8 fa0[4], fa1[4], fa2[4];
      #pragma unroll
      for (int f = 0; f < 4; ++f) {
        int ai = sg * 1024 + (wr * 64 + f * 16 + (lane & 15)) * 8;
        fa0[f] = *(const short8*)&Ab[ai];
        fa1[f] = *(const short8*)&Ab[8192 + ai];
        fa2[f] = *(const short8*)&Ab[16384 + ai];
      }
      short8 fb[4];
      #pragma unroll
      for (int p = 0; p < 3; ++p) {
        #pragma unroll
        for (int f = 0; f < 4; ++f) {
          if (var == 0) {
            fb[f] = *(const short8*)&Bs[p * 8192 + sg * 1024
                                        + (chh * 64 + f * 16 + (lane & 15)) * 8];
          } else {
            short8 v = *(const short8*)&Bs[p * 8192 + (7 - sg) * 1024
                                           + (chh * 64 + 63 - (f * 16 + (lane & 15))) * 8];
            i32x4 vi = __builtin_bit_cast(i32x4, v);
            i32x4 wo;
            wo.x = rot16(vi.w); wo.y = rot16(vi.z);
            wo.z = rot16(vi.y); wo.w = rot16(vi.x);
            fb[f] = __builtin_bit_cast(short8, wo);
          }
        }
        if (p == 0) {
          #pragma unroll
          for (int fi = 0; fi < 4; ++fi)
            #pragma unroll
            for (int fj = 0; fj < 4; ++fj) {
              accM[fi][fj] = __builtin_amdgcn_mfma_f32_16x16x32_bf16(fa0[fi], fb[fj], accM[fi][fj], 0, 0, 0);
              accL[fi][fj] = __builtin_amdgcn_mfma_f32_16x16x32_bf16(fa1[fi], fb[fj], accL[fi][fj], 0, 0, 0);
              accL[fi][fj] = __builtin_amdgcn_mfma_f32_16x16x32_bf16(fa2[fi], fb[fj], accL[fi][fj], 0, 0, 0);
            }
        } else if (p == 1) {
          #pragma unroll
          for (int fi = 0; fi < 4; ++fi)
            #pragma unroll
            for (int fj = 0; fj < 4; ++fj) {
              accL[fi][fj] = __builtin_amdgcn_mfma_f32_16x16x32_bf16(fa0[fi], fb[fj], accL[fi][fj], 0, 0, 0);
              accL[fi][fj] = __builtin_amdgcn_mfma_f32_16x16x32_bf16(fa1[fi], fb[fj], accL[fi][fj], 0, 0, 0);
            }
        } else {
          #pragma unroll
          for (int fi = 0; fi < 4; ++fi)
            #pragma unroll
            for (int fj = 0; fj < 4; ++fj)
              accL[fi][fj] = __builtin_amdgcn_mfma_f32_16x16x32_bf16(fa0[fi], fb[fj], accL[fi][fj], 0, 0, 0);
        }
      }
    }
  };

  issueB(0);
  issueA(0, 0);
  writeB();
  __syncthreads();

  for (int kt = 0; kt < 64; ++kt) {
    if (kt < 63) { issueB(kt + 1); issueA(kt + 1, (kt + 1) & 1); }
    __builtin_amdgcn_sched_barrier(0);     // pin issues ABOVE the MFMA cluster
    __builtin_amdgcn_s_setprio(1);
    compute(kt & 1);
    __builtin_amdgcn_s_setprio(0);
    __syncthreads();
    if (kt < 63) writeB();
    __syncthreads();
  }

  // ---- epilogue: var=1 publishes b via LDS; var=0 fuses cos(atan2) ----
  float* bx = (float*)lds;
  const int g = wr * 2 + chh;
  if (var) {
    #pragma unroll
    for (int fi = 0; fi < 4; ++fi)
      #pragma unroll
      for (int fj = 0; fj < 4; ++fj)
        #pragma unroll
        for (int r = 0; r < 4; ++r)
          bx[g * 4096 + (fi * 16 + ((lane >> 4) << 2) + r) * 64 + fj * 16 + (lane & 15)]
            = accM[fi][fj][r] + accL[fi][fj][r];
  }
  __syncthreads();
  if (!var) {
    #pragma unroll
    for (int fi = 0; fi < 4; ++fi) {
      #pragma unroll
      for (int fj = 0; fj < 4; ++fj) {
        #pragma unroll
        for (int r = 0; r < 4; ++r) {
          int rl = fi * 16 + ((lane >> 4) << 2) + r;
          int cl = fj * 16 + (lane & 15);
          float a = accM[fi][fj][r] + accL[fi][fj][r];
          float b = bx[g * 4096 + rl * 64 + cl];
          float r2 = a * a + b * b;
          float cp = (r2 > 0.0f) ? (a / sqrtf(r2)) : 1.0f;   // cos(atan2(b,a))
          int row = bm + wr * 64 + rl;
          int c   = d2 * 128 + chh * 64 + cl;
          cosp[(size_t)row * 2048 + c] = cp;
          if (bm == 0 && wr == 0) xh64[row * 2048 + c] = a;
        }
      }
    }
  }
}

// ---------------- row n=2048, stage 1: partial dots (512 blocks) ------------
// Block (s, d): p-slice [s*256, s*256+256) of batch d. Thread t = ph*128+var*64+m
// sums 128 p's; pairs reduced in LDS; partial -> P[s][d][var*64+m].
__global__ __launch_bounds__(256) void gemv_part(const float* __restrict__ x,
                                                 float* __restrict__ P) {
  __shared__ float casL[256];
  __shared__ float red[256];
  const int t = threadIdx.x;
  const int s = blockIdx.x;                // p-slice
  const int d = blockIdx.y;                // batch
  const float t1 = TPI * 2048.0f;          // exact pow2-scale multiply
  {
    int p = s * 256 + t;
    float arg = (t1 * (float)p) * (1.0f / 4096.0f);
    casL[t] = cosf(arg) + sinf(arg);
  }
  __syncthreads();
  const int m   = t & 63;
  const int var = (t >> 6) & 1;
  const int ph  = t >> 7;
  const float* xb = x + d * 262144;
  float sum = 0.0f;
  for (int i = 0; i < 128; ++i) {
    int pl = ph * 128 + i;
    int j2 = (s * 256 + pl) * 64 + m;
    int off = var ? ((j2 & ~4095) + 4095 - (j2 & 4095)) : j2;
    sum += casL[pl] * xb[off];
  }
  red[t] = sum;
  __syncthreads();
  if (t < 128)
    P[((size_t)s * 32 + d) * 128 + t] = red[t] + red[t + 128];
}

// ---------------- row n=2048, stage 2: reduce + cos(atan2) ------------------
__global__ __launch_bounds__(128) void gemv_red(const float* __restrict__ P,
                                                float* __restrict__ cosp) {
  __shared__ float ab[128];
  const int t = threadIdx.x;
  const int d = blockIdx.x;
  float sum = 0.0f;
  for (int s = 0; s < 16; ++s)
    sum += P[((size_t)s * 32 + d) * 128 + t];
  ab[t] = sum;
  __syncthreads();
  if (t < 64) {
    float a = ab[t], b = ab[64 + t];
    float r2 = a * a + b * b;
    float cp = (r2 > 0.0f) ? (a / sqrtf(r2)) : 1.0f;
    cosp[(size_t)2048 * 2048 + d * 64 + t] = cp;
  }
}

// ---------------- compl_mul: out_ht[b,o,m], modes=64 ------------------------
__global__ __launch_bounds__(256) void complmul(const float* __restrict__ xh64,
                                                const float* __restrict__ W,
                                                float* __restrict__ oh) {
  __shared__ float cl[64 * 65];
  const int t  = threadIdx.x;
  const int bq = blockIdx.y;
  const int og = blockIdx.x;
  #pragma unroll
  for (int e = 0; e < 16; ++e) {
    int idx = t + e * 256;
    int i = idx & 63, m = idx >> 6;
    cl[m * 65 + i] = xh64[m * 2048 + bq * 64 + i];
  }
  __syncthreads();
  const int m  = t & 63;
  const int o  = og * 4 + (t >> 6);
  const int mn = (64 - m) & 63;
  float s = 0.0f;
  for (int i = 0; i < 64; ++i) {
    float w  = W[i * 4096 + o * 64 + m];
    float wn = W[i * 4096 + o * 64 + mn];
    s += cl[m * 65 + i] * (w + wn) + cl[mn * 65 + i] * (w - wn);
  }
  oh[bq * 4096 + o * 64 + m] = 0.5f * s;
}

// ---------------- final: xi (sparse 64-term) * cosp -------------------------
__global__ __launch_bounds__(256) void final_k(const float* __restrict__ cosp,
                                               const float* __restrict__ tab,
                                               const float* __restrict__ oh,
                                               float* __restrict__ out) {
  __shared__ float tl[128 * 32];
  __shared__ float ol[64 * 64];
  const int t  = threadIdx.x;
  const int d  = blockIdx.y;
  const int n0 = blockIdx.x * 32;
  #pragma unroll
  for (int e = 0; e < 16; ++e) {
    int idx = t + e * 256;
    tl[idx] = tab[(idx >> 5) * TABST + n0 + (idx & 31)];
  }
  #pragma unroll
  for (int e = 0; e < 16; ++e) {
    int idx = t + e * 256;
    ol[idx] = oh[d * 4096 + idx];
  }
  __syncthreads();
  const int mp   = t & 63;
  const int nsub = t >> 6;

  float ohreg[64];
  #pragma unroll
  for (int c = 0; c < 64; ++c)
    ohreg[c] = ol[c * 64 + ((mp - c) & 63)];

  float acc[8] = {};
  #pragma unroll
  for (int c = 0; c < 64; ++c) {
    const float* tp = &tl[(2 * c + (c > mp ? 1 : 0)) * 32 + nsub * 8];
    float tv[8];
    *(float4*)&tv[0] = *(const float4*)tp;
    *(float4*)&tv[4] = *(const float4*)(tp + 4);
    #pragma unroll
    for (int q = 0; q < 8; ++q) acc[q] += tv[q] * ohreg[c];
  }
  #pragma unroll
  for (int q = 0; q < 8; ++q) {
    int np = n0 + nsub * 8 + q;
    if (np < KHT) {
      float cp = cosp[(size_t)np * 2048 + d * 64 + mp];
      out[d * 131136 + mp * 2049 + np] = acc[q] * cp;
    }
  }
}

extern "C" void kernel_launch(void* const* d_in, const int* in_sizes, int n_in,
                              void* d_out, int out_size, void* d_ws, size_t ws_size,
                              hipStream_t stream) {
  const float* x = (const float*)d_in[0];     // (32, 64, 4096) f32
  const float* W = (const float*)d_in[1];     // (64, 64, 64) f32
  float* out = (float*)d_out;                 // (32, 64, 2049) f32
  float* ws  = (float*)d_ws;

  short* Aq    = (short*)ws;
  float* cospB = ws + COSP_OFF;
  float* xh64  = ws + XH_OFF;
  float* tab   = ws + TAB_OFF;
  float* oh    = ws + OH_OFF;
  float* Pp    = ws + P_OFF;

  prep_A   <<<dim3(8, 512), dim3(256), 0, stream>>>(Aq);
  prep_tab <<<dim3((128 * TABST + 255) / 256), dim3(256), 0, stream>>>(tab);
  gemm_mfma<<<dim3(16, 16), dim3(512), 0, stream>>>(Aq, x, cospB, xh64);
  gemv_part<<<dim3(16, BATCH), dim3(256), 0, stream>>>(x, Pp);
  gemv_red <<<dim3(BATCH), dim3(128), 0, stream>>>(Pp, cospB);
  complmul <<<dim3(16, BATCH), dim3(256), 0, stream>>>(xh64, W, oh);
  final_k  <<<dim3(65, BATCH), dim3(256), 0, stream>>>(cospB, tab, oh, out);
}